// Round 7
// baseline (83.712 us; speedup 1.0000x reference)
//
#include <hip/hip_runtime.h>
#include <math.h>

#define D_MODEL   2048
#define N_EXPERTS 64
#define TOP_K     8
#define N_TOKENS  16384
#define TOK_TILE  64
#define NTHREADS  1024
#define NCHUNK    32               // 64 floats of K per chunk
// ws layout: [chunk:32][ks:2][cg:4][p:3][lane:64][16B] = 32*24576 bytes
#define WS_NEED   (32*24576)       // 786432 bytes

#define A_BUF     24576            // one A chunk buffer (bytes)
#define B_REGION  73728            // 3 A buffers, then 3 B buffers
#define SMEM_BYTES 147456

typedef __attribute__((ext_vector_type(8))) short bf16x8;
typedef __attribute__((ext_vector_type(4))) float f32x4;
typedef __attribute__((ext_vector_type(4))) int   i32x4;

union FragU { i32x4 i; bf16x8 h; };

// exact 3-way truncation split: x == h+m+l + eps, |eps| <= 2^-24 |x|
__device__ __forceinline__ void split3(float x, unsigned &h, unsigned &m, unsigned &l) {
    unsigned ux = __float_as_uint(x);
    h = ux & 0xffff0000u;
    float mf = x - __uint_as_float(h);       // exact (Sterbenz)
    unsigned um = __float_as_uint(mf) & 0xffff0000u;
    float lf = mf - __uint_as_float(um);     // exact
    m = um;
    l = __float_as_uint(lf) & 0xffff0000u;
}

__device__ __forceinline__ void async_cp16(const void* g, void* l) {
    __builtin_amdgcn_global_load_lds(
        (const __attribute__((address_space(1))) void*)g,
        (__attribute__((address_space(3))) void*)l, 16, 0, 0);
}

// ws pre-pack into fragment order: [chunk][ks][cg][p][lane][16B]
// frag (R2-HW-proven): expert = 16*cg + (lane&15), k = 64*chunk + 32*ks + 8*(lane>>4) + elem
__global__ __launch_bounds__(256) void pack_w_kernel(const float* __restrict__ gw,
                                                     unsigned* __restrict__ wp) {
    const int g    = blockIdx.x * 256 + threadIdx.x;   // dword id, 0..196607
    const int dw   = g & 3;
    const int lane = (g >> 2) & 63;
    const int u    = g >> 8;            // 0..767
    const int p    = u % 3;
    const int v2   = u / 3;             // 0..255
    const int cg   = v2 & 3;
    const int ks   = (v2 >> 2) & 1;
    const int chunk= v2 >> 3;           // 0..31
    const int e    = cg * 16 + (lane & 15);
    const int k    = chunk * 64 + ks * 32 + (lane >> 4) * 8 + dw * 2;
    const float w0 = gw[(size_t)e * D_MODEL + k];
    const float w1 = gw[(size_t)e * D_MODEL + k + 1];
    unsigned h0, m0, l0, h1, m1, l1;
    split3(w0, h0, m0, l0);
    split3(w1, h1, m1, l1);
    const unsigned c0 = (p == 0) ? h0 : ((p == 1) ? m0 : l0);
    const unsigned c1 = (p == 0) ? h1 : ((p == 1) ? m1 : l1);
    wp[g] = (c0 >> 16) | c1;            // low short = elem0
}

// convert 4 fp32 -> 3 planes x 4 bf16, write 8B per plane (fragment-ordered LDS)
__device__ __forceinline__ void conv_write(const float4 v, char* p0) {
    unsigned h0,m0_,l0, h1,m1,l1, h2,m2,l2, h3,m3,l3;
    split3(v.x, h0, m0_, l0);
    split3(v.y, h1, m1, l1);
    split3(v.z, h2, m2, l2);
    split3(v.w, h3, m3, l3);
    uint2 hw, mw, lw;
    hw.x = (h0 >> 16) | h1;  hw.y = (h2 >> 16) | h3;
    mw.x = (m0_>> 16) | m1;  mw.y = (m2 >> 16) | m3;
    lw.x = (l0 >> 16) | l1;  lw.y = (l2 >> 16) | l3;
    *(uint2*)(p0)        = hw;
    *(uint2*)(p0 + 1024) = mw;
    *(uint2*)(p0 + 2048) = lw;
}

#define MFMA(A_, B_, C_) C_ = __builtin_amdgcn_mfma_f32_16x16x32_bf16((A_).h, (B_).h, C_, 0, 0, 0)

__global__ __launch_bounds__(NTHREADS, 4) void router_mfma(
    const float* __restrict__ x, const unsigned* __restrict__ wp,
    float* __restrict__ out)
{
    // manual arena: A planes [3buf][2ks][4rg][3p][64][16B], then B same with cg
    __shared__ __align__(16) char smem[SMEM_BYTES];

    const int tid  = threadIdx.x;
    const int lane = tid & 63;
    const int w    = tid >> 6;           // 0..15
    const int m0   = blockIdx.x * TOK_TILE;

    // compute roles: 4 rowgroups x 4 expertgroups, full K per wave
    const int r    = w & 3;
    const int cg   = w >> 2;
    const int lrow = lane & 15;
    const int lk   = lane >> 4;

    // ---- x staging roles: thread -> (ks, rg, fraglane, half) ----
    const int sk  = (tid >> 9) & 1;
    const int srg = (tid >> 7) & 3;
    const int sln = (tid >> 1) & 63;
    const int sh  = tid & 1;
    const float* xsrc = x + (size_t)(m0 + srg * 16 + (sln & 15)) * D_MODEL
                        + sk * 32 + (sln >> 4) * 8 + sh * 4;
    const int aw0 = (sk * 4 + srg) * 3072 + sln * 16 + sh * 8;   // plane-0 byte offset in A buf

    // ---- B staging: 24 1KB copies + 8 benign duplicates -> 2 per wave ----
    const int j0 = (2 * w) % 24, j1 = (2 * w + 1) % 24;
    const char* wsrc0 = (const char*)wp + j0 * 1024 + lane * 16;
    const char* wsrc1 = (const char*)wp + j1 * 1024 + lane * 16;

    // ---- compute read offsets (all lane-linear: zero bank conflicts) ----
    const int aofs = r  * 3072 + lane * 16;              // + ks*12288 + p*1024
    const int bofs = B_REGION + cg * 3072 + lane * 16;

    f32x4 accA = {0.f, 0.f, 0.f, 0.f};
    f32x4 accB = accA;

#define STAGE_AND_WAIT(c, CUR, NXT, WAITSTR)                                   \
    {                                                                          \
        if ((c) + 1 < NCHUNK) {                                                \
            const int bw_ = ((c) + 1) % 3;                                     \
            char* bb_ = smem + B_REGION + bw_ * 24576;                         \
            /* B gloads FIRST (oldest = retired by vmcnt(1), x stays flying)*/ \
            async_cp16(wsrc0 + ((c) + 1) * 24576, bb_ + j0 * 1024);            \
            async_cp16(wsrc1 + ((c) + 1) * 24576, bb_ + j1 * 1024);            \
            if ((c) + 2 < NCHUNK) NXT = *(const float4*)(xsrc + ((c) + 2) * 64); \
            conv_write(CUR, smem + bw_ * A_BUF + aw0);                         \
        }                                                                      \
        asm volatile("s_waitcnt " WAITSTR " lgkmcnt(0)" ::: "memory");         \
        __builtin_amdgcn_sched_barrier(0);                                     \
        __builtin_amdgcn_s_barrier();                                          \
        __builtin_amdgcn_sched_barrier(0);                                     \
    }

#define COMPUTE(c)                                                             \
    {                                                                          \
        const char* cb_ = smem + ((c) % 3) * 24576;                            \
        _Pragma("unroll")                                                      \
        for (int ks = 0; ks < 2; ++ks) {                                       \
            const char* ap_ = cb_ + ks * 12288 + aofs;                         \
            const char* bp_ = cb_ + ks * 12288 + bofs;                         \
            FragU ah, am_, al, bh, bm, bl;                                     \
            ah.i  = *(const i32x4*)(ap_);                                      \
            am_.i = *(const i32x4*)(ap_ + 1024);                               \
            al.i  = *(const i32x4*)(ap_ + 2048);                               \
            bh.i  = *(const i32x4*)(bp_);                                      \
            bm.i  = *(const i32x4*)(bp_ + 1024);                               \
            bl.i  = *(const i32x4*)(bp_ + 2048);                               \
            MFMA(ah, bh, accA); MFMA(am_, bh, accA); MFMA(al, bh, accA);       \
            MFMA(ah, bm, accB); MFMA(am_, bm, accB); MFMA(ah, bl, accB);       \
        }                                                                      \
    }

    float4 X, Y;
    {   // prologue: B(0) + x(0),x(1); convert x(0) -> Abuf0; publish buf0
        async_cp16(wsrc0, smem + B_REGION + j0 * 1024);
        async_cp16(wsrc1, smem + B_REGION + j1 * 1024);
        float4 T = *(const float4*)(xsrc);        // x(0)
        X = *(const float4*)(xsrc + 64);          // x(1)
        conv_write(T, smem + aw0);                // implicit wait retires B(0)+x(0), keeps x(1)
        asm volatile("s_waitcnt lgkmcnt(0)" ::: "memory");
        __builtin_amdgcn_sched_barrier(0);
        __builtin_amdgcn_s_barrier();
        __builtin_amdgcn_sched_barrier(0);
    }

    for (int c = 0; c < 28; c += 2) {
        STAGE_AND_WAIT(c,     X, Y, "vmcnt(1)"); COMPUTE(c);
        STAGE_AND_WAIT(c + 1, Y, X, "vmcnt(1)"); COMPUTE(c + 1);
    }
    STAGE_AND_WAIT(28, X, Y, "vmcnt(1)"); COMPUTE(28);
    STAGE_AND_WAIT(29, Y, X, "vmcnt(1)"); COMPUTE(29);
    STAGE_AND_WAIT(30, X, Y, "vmcnt(2)"); COMPUTE(30);   // only B(31) in flight: free
    STAGE_AND_WAIT(31, Y, X, "vmcnt(0)"); COMPUTE(31);   // drain B(31) before last compute

#undef STAGE_AND_WAIT
#undef COMPUTE

    // ---- lt overlaps Abuf0 (17KB < 24KB); COMPUTE(31) uses buf1 -> disjoint ----
    float (*lt)[N_EXPERTS + 1] = (float (*)[N_EXPERTS + 1])smem;
    float* smax = (float*)smem + TOK_TILE * (N_EXPERTS + 1);
    float* srs  = smax + TOK_TILE;

    // C layout (R2-HW-proven): col = lane&15, row = (lane>>4)*4 + reg
#pragma unroll
    for (int reg = 0; reg < 4; ++reg)
        lt[r * 16 + lk * 4 + reg][cg * 16 + lrow] = accA[reg] + accB[reg];
    __syncthreads();

    float* out_idx = out;
    float* out_w   = out + (size_t)N_TOKENS * TOP_K;
    float* out_p   = out + (size_t)2 * N_TOKENS * TOP_K;
    float* out_l   = out_p + (size_t)N_TOKENS * N_EXPERTS;

    if (tid < TOK_TILE) {
        const int t = tid;
        float tv[TOP_K];
        int   ti[TOP_K];
#pragma unroll
        for (int i = 0; i < TOP_K; ++i) { tv[i] = -INFINITY; ti[i] = 0; }
        float m = -INFINITY;

        for (int e = 0; e < N_EXPERTS; ++e) {
            const float v = lt[t][e];
            m = fmaxf(m, v);
            if (v > tv[TOP_K - 1]) {
#pragma unroll
                for (int j = TOP_K - 1; j >= 1; --j) {
                    const bool shift = (v > tv[j - 1]);
                    const bool here  = (v > tv[j]);
                    const float ntv = shift ? tv[j - 1] : (here ? v : tv[j]);
                    const int   nti = shift ? ti[j - 1] : (here ? e : ti[j]);
                    tv[j] = ntv; ti[j] = nti;
                }
                if (v > tv[0]) { tv[0] = v; ti[0] = e; }
            }
        }

        float s = 0.f;
        for (int e = 0; e < N_EXPERTS; ++e) s += expf(lt[t][e] - m);
        const float rs = 1.f / s;
        smax[t] = m;
        srs[t]  = rs;

        float ex[TOP_K];
        float wsum = 0.f;
#pragma unroll
        for (int i = 0; i < TOP_K; ++i) { ex[i] = expf(tv[i] - tv[0]); wsum += ex[i]; }
        const float rw = 1.f / wsum;

        const int tok = m0 + t;
#pragma unroll
        for (int i = 0; i < TOP_K; ++i) {
            out_idx[(size_t)tok * TOP_K + i] = (float)ti[i];
            out_w  [(size_t)tok * TOP_K + i] = ex[i] * rw;
        }
    }
    __syncthreads();

    // 64x64 floats = 1024 threads x 1 float4, coalesced
    {
        const int f = tid * 4;
        const int t = f >> 6;
        const int e = f & 63;
        const float l0 = lt[t][e + 0];
        const float l1 = lt[t][e + 1];
        const float l2 = lt[t][e + 2];
        const float l3 = lt[t][e + 3];
        const float mm = smax[t];
        const float rr = srs[t];
        float4 pv = make_float4(expf(l0 - mm) * rr, expf(l1 - mm) * rr,
                                expf(l2 - mm) * rr, expf(l3 - mm) * rr);
        float4 lv = make_float4(l0, l1, l2, l3);
        const size_t gbase = (size_t)m0 * N_EXPERTS + f;
        *(float4*)(out_p + gbase) = pv;
        *(float4*)(out_l + gbase) = lv;
    }
}

// ---------------- fallback (R0-proven fp32 path) if ws too small ----------------
__global__ __launch_bounds__(512) void router_fallback(
    const float* __restrict__ x, const float* __restrict__ gw,
    float* __restrict__ out)
{
    __shared__ float xs[64][33];
    __shared__ float wsh[N_EXPERTS][36];
    __shared__ float lt[64][N_EXPERTS + 1];
    __shared__ float smax[64], srs[64];

    const int tid  = threadIdx.x;
    const int lane = tid & 63;
    const int wv   = tid >> 6;
    const int m0   = blockIdx.x * 64;
    const int srow = tid >> 3;
    const int skq  = (tid & 7) * 4;

    const float* xsrc = x  + (size_t)(m0 + srow) * D_MODEL + skq;
    const float* wsrc = gw + (size_t)srow        * D_MODEL + skq;
    float4 xr = *(const float4*)(xsrc);
    float4 wr = *(const float4*)(wsrc);

    float acc[8];
#pragma unroll
    for (int i = 0; i < 8; ++i) acc[i] = 0.f;
    const int e0 = wv * 8;

    for (int c = 0; c < D_MODEL / 32; ++c) {
        xs[srow][skq] = xr.x; xs[srow][skq+1] = xr.y; xs[srow][skq+2] = xr.z; xs[srow][skq+3] = xr.w;
        *(float4*)&wsh[srow][skq] = wr;
        __syncthreads();
        if (c + 1 < D_MODEL / 32) {
            xr = *(const float4*)(xsrc + (c + 1) * 32);
            wr = *(const float4*)(wsrc + (c + 1) * 32);
        }
#pragma unroll 8
        for (int k4 = 0; k4 < 8; ++k4) {
            const float4 xv = *(const float4*)&xs[lane][k4 * 4];
#pragma unroll
            for (int e = 0; e < 8; ++e) {
                const float4 w4 = *(const float4*)&wsh[e0 + e][k4 * 4];
                acc[e] = fmaf(xv.x, w4.x, fmaf(xv.y, w4.y, fmaf(xv.z, w4.z, fmaf(xv.w, w4.w, acc[e]))));
            }
        }
        __syncthreads();
    }
#pragma unroll
    for (int e = 0; e < 8; ++e) lt[lane][e0 + e] = acc[e];
    __syncthreads();

    float* out_idx = out;
    float* out_w   = out + (size_t)N_TOKENS * TOP_K;
    float* out_p   = out + (size_t)2 * N_TOKENS * TOP_K;
    float* out_l   = out_p + (size_t)N_TOKENS * N_EXPERTS;

    if (tid < 64) {
        const int t = tid;
        float tv[TOP_K]; int ti[TOP_K];
#pragma unroll
        for (int i = 0; i < TOP_K; ++i) { tv[i] = -INFINITY; ti[i] = 0; }
        float m = -INFINITY;
        for (int e = 0; e < N_EXPERTS; ++e) {
            const float v = lt[t][e];
            m = fmaxf(m, v);
            if (v > tv[TOP_K - 1]) {
#pragma unroll
                for (int j = TOP_K - 1; j >= 1; --j) {
                    const bool shift = (v > tv[j - 1]);
                    const bool here  = (v > tv[j]);
                    const float ntv = shift ? tv[j - 1] : (here ? v : tv[j]);
                    const int   nti = shift ? ti[j - 1] : (here ? e : ti[j]);
                    tv[j] = ntv; ti[j] = nti;
                }
                if (v > tv[0]) { tv[0] = v; ti[0] = e; }
            }
        }
        float s = 0.f;
        for (int e = 0; e < N_EXPERTS; ++e) s += expf(lt[t][e] - m);
        const float rs = 1.f / s;
        smax[t] = m; srs[t] = rs;
        float ex[TOP_K]; float wsum = 0.f;
#pragma unroll
        for (int i = 0; i < TOP_K; ++i) { ex[i] = expf(tv[i] - tv[0]); wsum += ex[i]; }
        const float rw = 1.f / wsum;
        const int tok = m0 + t;
#pragma unroll
        for (int i = 0; i < TOP_K; ++i) {
            out_idx[(size_t)tok * TOP_K + i] = (float)ti[i];
            out_w  [(size_t)tok * TOP_K + i] = ex[i] * rw;
        }
    }
    __syncthreads();
#pragma unroll
    for (int rep = 0; rep < 2; ++rep) {
        const int f = rep * (512 * 4) + tid * 4;
        const int t = f >> 6;
        const int e = f & 63;
        const float l0 = lt[t][e], l1 = lt[t][e+1], l2 = lt[t][e+2], l3 = lt[t][e+3];
        const float mm = smax[t], rr = srs[t];
        float4 pv = make_float4(expf(l0-mm)*rr, expf(l1-mm)*rr, expf(l2-mm)*rr, expf(l3-mm)*rr);
        float4 lv = make_float4(l0, l1, l2, l3);
        const size_t gbase = (size_t)m0 * N_EXPERTS + f;
        *(float4*)(out_p + gbase) = pv;
        *(float4*)(out_l + gbase) = lv;
    }
}

extern "C" void kernel_launch(void* const* d_in, const int* in_sizes, int n_in,
                              void* d_out, int out_size, void* d_ws, size_t ws_size,
                              hipStream_t stream) {
    const float* x  = (const float*)d_in[0];
    const float* gw = (const float*)d_in[1];
    float* out = (float*)d_out;
    if (ws_size >= (size_t)WS_NEED) {
        unsigned* wp = (unsigned*)d_ws;
        pack_w_kernel<<<dim3(WS_NEED / 4 / 256), dim3(256), 0, stream>>>(gw, wp);
        router_mfma<<<dim3(N_TOKENS / TOK_TILE), dim3(NTHREADS), 0, stream>>>(x, wp, out);
    } else {
        router_fallback<<<dim3(N_TOKENS / 64), dim3(512), 0, stream>>>(x, gw, out);
    }
}

// Round 8
// 81.778 us; speedup vs baseline: 1.0237x; 1.0237x over previous
//
#include <hip/hip_runtime.h>
#include <math.h>

#define D_MODEL   2048
#define N_EXPERTS 64
#define TOP_K     8
#define N_TOKENS  16384
#define NTHREADS  256
// ws layout (R2-HW-proven): [kstep 0..63][fr 0..3][ver 0..2][lane 0..63][4 dw]
#define WS_NEED   (64*4*3*64*16)   // 786432 bytes

typedef __attribute__((ext_vector_type(8))) short bf16x8;
typedef __attribute__((ext_vector_type(4))) float f32x4;
typedef __attribute__((ext_vector_type(4))) int   i32x4;

union FragU { i32x4 i; bf16x8 h; };

// exact 3-way truncation split: x == h+m+l + eps, |eps| <= 2^-24 |x|
__device__ __forceinline__ void split3(float x, unsigned &h, unsigned &m, unsigned &l) {
    unsigned ux = __float_as_uint(x);
    h = ux & 0xffff0000u;
    float mf = x - __uint_as_float(h);       // exact (Sterbenz)
    unsigned um = __float_as_uint(mf) & 0xffff0000u;
    float lf = mf - __uint_as_float(um);     // exact
    m = um;
    l = __float_as_uint(lf) & 0xffff0000u;
}

// ---- verbatim from R2 (HW-proven numerics + layout) ----
__global__ __launch_bounds__(256) void pack_w_kernel(const float* __restrict__ gw,
                                                     unsigned* __restrict__ wp) {
    const int g    = blockIdx.x * 256 + threadIdx.x;   // 0..196607
    const int d    = g & 3;
    const int lane = (g >> 2) & 63;
    const int rest = g >> 8;                           // 0..767
    const int v    = rest % 3;
    const int t    = rest / 3;                         // ks*4 + fr
    const int fr   = t & 3;
    const int ks   = t >> 2;
    const int e    = fr * 16 + (lane & 15);            // B col = lane&15
    const int k    = ks * 32 + (lane >> 4) * 8 + 2 * d;
    const float w0 = gw[(size_t)e * D_MODEL + k];
    const float w1 = gw[(size_t)e * D_MODEL + k + 1];
    unsigned h0, m0, l0, h1, m1, l1;
    split3(w0, h0, m0, l0);
    split3(w1, h1, m1, l1);
    const unsigned c0 = (v == 0) ? h0 : ((v == 1) ? m0 : l0);
    const unsigned c1 = (v == 0) ? h1 : ((v == 1) ? m1 : l1);
    wp[g] = (c0 >> 16) | c1;                           // low short = elem0
}

__device__ __forceinline__ void splitpack(const float4 a, const float4 b,
                                          FragU &ph, FragU &pm, FragU &pl) {
    const float f[8] = {a.x, a.y, a.z, a.w, b.x, b.y, b.z, b.w};
#pragma unroll
    for (int d = 0; d < 4; ++d) {
        unsigned h0, m0, l0, h1, m1, l1;
        split3(f[2 * d],     h0, m0, l0);
        split3(f[2 * d + 1], h1, m1, l1);
        ph.i[d] = (int)((h0 >> 16) | h1);
        pm.i[d] = (int)((m0 >> 16) | m1);
        pl.i[d] = (int)((l0 >> 16) | l1);
    }
}

#define MFMA(A_, B_, C_) C_ = __builtin_amdgcn_mfma_f32_16x16x32_bf16((A_).h, (B_).h, C_, 0, 0, 0)

// 6-term split product for one expert fragment, 2 independent acc chains
#define FRAG6(Bh_, Bm_, Bl_, ACCA_, ACCB_)                                   \
    {                                                                        \
        FragU bh_, bm_, bl_;                                                 \
        bh_.i = Bh_; bm_.i = Bm_; bl_.i = Bl_;                               \
        MFMA(ah, bh_, ACCA_); MFMA(am_, bh_, ACCA_); MFMA(al, bh_, ACCA_);   \
        MFMA(ah, bm_, ACCB_); MFMA(am_, bm_, ACCB_); MFMA(ah, bl_, ACCB_);   \
    }

// Barrier-free main loop: block = 4 independent waves = 4 K-quarters of one
// 16-token tile. No __syncthreads until the final cross-wave reduce.
__global__ __launch_bounds__(NTHREADS, 4) void router_mfma(
    const float* __restrict__ x, const unsigned* __restrict__ wp,
    float* __restrict__ out)
{
    // partials: [q:4][tok:16][expert:64] with token stride 68 (2-way banks =
    // free, m136); + smax/srs. 17.5 KB -> 4 blocks/CU co-resident.
    __shared__ __align__(16) float part[4 * 1088 + 32];

    const int tid  = threadIdx.x;
    const int lane = tid & 63;
    const int q    = tid >> 6;          // K-quarter 0..3
    const int m0   = blockIdx.x * 16;

    const int lrow = lane & 15;         // A row / C col
    const int lk   = lane >> 4;         // k-group 0..3

    // A gather (R2-proven fragment): lane reads x[m0+lrow][q*512 + s*32 + lk*8 ..+8]
    const float* xa = x + (size_t)(m0 + lrow) * D_MODEL + q * 512 + lk * 8;
    // B base for this wave's K-quarter (dwords)
    const unsigned* wb = wp + (size_t)q * 49152 + lane * 4;

    f32x4 acc0a = {0.f,0.f,0.f,0.f}, acc0b = acc0a;
    f32x4 acc1a = acc0a, acc1b = acc0a;
    f32x4 acc2a = acc0a, acc2b = acc0a;
    f32x4 acc3a = acc0a, acc3b = acc0a;

    // preload A(0)
    float4 Aa = *(const float4*)(xa);
    float4 Ab = *(const float4*)(xa + 4);

#pragma unroll 2
    for (int s = 0; s < 16; ++s) {
        // B first (L2; oldest in vmcnt queue -> consumed w/o draining A)
        const unsigned* bt = wb + s * 3072;
        const i32x4 B0h = *(const i32x4*)(bt +    0);
        const i32x4 B0m = *(const i32x4*)(bt +  256);
        const i32x4 B0l = *(const i32x4*)(bt +  512);
        const i32x4 B1h = *(const i32x4*)(bt +  768);
        const i32x4 B1m = *(const i32x4*)(bt + 1024);
        const i32x4 B1l = *(const i32x4*)(bt + 1280);
        const i32x4 B2h = *(const i32x4*)(bt + 1536);
        const i32x4 B2m = *(const i32x4*)(bt + 1792);
        const i32x4 B2l = *(const i32x4*)(bt + 2048);
        const i32x4 B3h = *(const i32x4*)(bt + 2304);
        const i32x4 B3m = *(const i32x4*)(bt + 2560);
        const i32x4 B3l = *(const i32x4*)(bt + 2816);

        // A prefetch for s+1 (HBM; stays in flight under this kstep's MFMAs)
        float4 Na = Aa, Nb = Ab;
        if (s + 1 < 16) {
            Na = *(const float4*)(xa + (s + 1) * 32);
            Nb = *(const float4*)(xa + (s + 1) * 32 + 4);
        }

        FragU ah, am_, al;
        splitpack(Aa, Ab, ah, am_, al);

        FRAG6(B0h, B0m, B0l, acc0a, acc0b);
        FRAG6(B1h, B1m, B1l, acc1a, acc1b);
        FRAG6(B2h, B2m, B2l, acc2a, acc2b);
        FRAG6(B3h, B3m, B3l, acc3a, acc3b);

        Aa = Na; Ab = Nb;
    }

    // ---- write per-wave partials. C layout (R2-HW-proven):
    // token = lk*4 + reg, expert = fr*16 + lrow
    {
        float* ps = part + q * 1088;
#pragma unroll
        for (int reg = 0; reg < 4; ++reg) {
            const int tok = lk * 4 + reg;
            ps[tok * 68 +  0 + lrow] = acc0a[reg] + acc0b[reg];
            ps[tok * 68 + 16 + lrow] = acc1a[reg] + acc1b[reg];
            ps[tok * 68 + 32 + lrow] = acc2a[reg] + acc2b[reg];
            ps[tok * 68 + 48 + lrow] = acc3a[reg] + acc3b[reg];
        }
    }
    __syncthreads();

    // ---- reduce 4 K-quarters: thread j -> (tok = j>>4, e0 = (j&15)*4)
    {
        const int tok = tid >> 4;
        const int e0  = (tid & 15) * 4;
        const int o   = tok * 68 + e0;
        float4 s0 = *(const float4*)(part + 0 * 1088 + o);
        float4 s1 = *(const float4*)(part + 1 * 1088 + o);
        float4 s2 = *(const float4*)(part + 2 * 1088 + o);
        float4 s3 = *(const float4*)(part + 3 * 1088 + o);
        float4 r = make_float4(s0.x + s1.x + s2.x + s3.x,
                               s0.y + s1.y + s2.y + s3.y,
                               s0.z + s1.z + s2.z + s3.z,
                               s0.w + s1.w + s2.w + s3.w);
        *(float4*)(part + o) = r;     // slice 0 becomes lt[tok*68 + e]
    }
    __syncthreads();

    float* lt   = part;               // [tok*68 + e]
    float* smax = part + 4 * 1088;
    float* srs  = smax + 16;

    float* out_idx = out;
    float* out_w   = out + (size_t)N_TOKENS * TOP_K;
    float* out_p   = out + (size_t)2 * N_TOKENS * TOP_K;
    float* out_l   = out_p + (size_t)N_TOKENS * N_EXPERTS;

    if (tid < 16) {
        const int t = tid;
        float tv[TOP_K];
        int   ti[TOP_K];
#pragma unroll
        for (int i = 0; i < TOP_K; ++i) { tv[i] = -INFINITY; ti[i] = 0; }
        float m = -INFINITY;

        for (int e = 0; e < N_EXPERTS; ++e) {
            const float v = lt[t * 68 + e];
            m = fmaxf(m, v);
            if (v > tv[TOP_K - 1]) {
#pragma unroll
                for (int j = TOP_K - 1; j >= 1; --j) {
                    const bool shift = (v > tv[j - 1]);
                    const bool here  = (v > tv[j]);
                    const float ntv = shift ? tv[j - 1] : (here ? v : tv[j]);
                    const int   nti = shift ? ti[j - 1] : (here ? e : ti[j]);
                    tv[j] = ntv; ti[j] = nti;
                }
                if (v > tv[0]) { tv[0] = v; ti[0] = e; }
            }
        }

        float s = 0.f;
        for (int e = 0; e < N_EXPERTS; ++e) s += expf(lt[t * 68 + e] - m);
        const float rs = 1.f / s;
        smax[t] = m;
        srs[t]  = rs;

        float ex[TOP_K];
        float wsum = 0.f;
#pragma unroll
        for (int i = 0; i < TOP_K; ++i) { ex[i] = expf(tv[i] - tv[0]); wsum += ex[i]; }
        const float rw = 1.f / wsum;

        const int tok = m0 + t;
#pragma unroll
        for (int i = 0; i < TOP_K; ++i) {
            out_idx[(size_t)tok * TOP_K + i] = (float)ti[i];
            out_w  [(size_t)tok * TOP_K + i] = ex[i] * rw;
        }
    }
    __syncthreads();

    // 16x64 floats = 256 threads x 1 float4, coalesced
    {
        const int f = tid * 4;
        const int t = f >> 6;
        const int e = f & 63;
        const float l0 = lt[t * 68 + e + 0];
        const float l1 = lt[t * 68 + e + 1];
        const float l2 = lt[t * 68 + e + 2];
        const float l3 = lt[t * 68 + e + 3];
        const float mm = smax[t];
        const float rr = srs[t];
        float4 pv = make_float4(expf(l0 - mm) * rr, expf(l1 - mm) * rr,
                                expf(l2 - mm) * rr, expf(l3 - mm) * rr);
        float4 lv = make_float4(l0, l1, l2, l3);
        const size_t gbase = (size_t)m0 * N_EXPERTS + f;
        *(float4*)(out_p + gbase) = pv;
        *(float4*)(out_l + gbase) = lv;
    }
}

// ---------------- fallback (R0-proven fp32 path) if ws too small ----------------
__global__ __launch_bounds__(512) void router_fallback(
    const float* __restrict__ x, const float* __restrict__ gw,
    float* __restrict__ out)
{
    __shared__ float xs[64][33];
    __shared__ float wsh[N_EXPERTS][36];
    __shared__ float lt[64][N_EXPERTS + 1];
    __shared__ float smax[64], srs[64];

    const int tid  = threadIdx.x;
    const int lane = tid & 63;
    const int wv   = tid >> 6;
    const int m0   = blockIdx.x * 64;
    const int srow = tid >> 3;
    const int skq  = (tid & 7) * 4;

    const float* xsrc = x  + (size_t)(m0 + srow) * D_MODEL + skq;
    const float* wsrc = gw + (size_t)srow        * D_MODEL + skq;
    float4 xr = *(const float4*)(xsrc);
    float4 wr = *(const float4*)(wsrc);

    float acc[8];
#pragma unroll
    for (int i = 0; i < 8; ++i) acc[i] = 0.f;
    const int e0 = wv * 8;

    for (int c = 0; c < D_MODEL / 32; ++c) {
        xs[srow][skq] = xr.x; xs[srow][skq+1] = xr.y; xs[srow][skq+2] = xr.z; xs[srow][skq+3] = xr.w;
        *(float4*)&wsh[srow][skq] = wr;
        __syncthreads();
        if (c + 1 < D_MODEL / 32) {
            xr = *(const float4*)(xsrc + (c + 1) * 32);
            wr = *(const float4*)(wsrc + (c + 1) * 32);
        }
#pragma unroll 8
        for (int k4 = 0; k4 < 8; ++k4) {
            const float4 xv = *(const float4*)&xs[lane][k4 * 4];
#pragma unroll
            for (int e = 0; e < 8; ++e) {
                const float4 w4 = *(const float4*)&wsh[e0 + e][k4 * 4];
                acc[e] = fmaf(xv.x, w4.x, fmaf(xv.y, w4.y, fmaf(xv.z, w4.z, fmaf(xv.w, w4.w, acc[e]))));
            }
        }
        __syncthreads();
    }
#pragma unroll
    for (int e = 0; e < 8; ++e) lt[lane][e0 + e] = acc[e];
    __syncthreads();

    float* out_idx = out;
    float* out_w   = out + (size_t)N_TOKENS * TOP_K;
    float* out_p   = out + (size_t)2 * N_TOKENS * TOP_K;
    float* out_l   = out_p + (size_t)N_TOKENS * N_EXPERTS;

    if (tid < 64) {
        const int t = tid;
        float tv[TOP_K]; int ti[TOP_K];
#pragma unroll
        for (int i = 0; i < TOP_K; ++i) { tv[i] = -INFINITY; ti[i] = 0; }
        float m = -INFINITY;
        for (int e = 0; e < N_EXPERTS; ++e) {
            const float v = lt[t][e];
            m = fmaxf(m, v);
            if (v > tv[TOP_K - 1]) {
#pragma unroll
                for (int j = TOP_K - 1; j >= 1; --j) {
                    const bool shift = (v > tv[j - 1]);
                    const bool here  = (v > tv[j]);
                    const float ntv = shift ? tv[j - 1] : (here ? v : tv[j]);
                    const int   nti = shift ? ti[j - 1] : (here ? e : ti[j]);
                    tv[j] = ntv; ti[j] = nti;
                }
                if (v > tv[0]) { tv[0] = v; ti[0] = e; }
            }
        }
        float s = 0.f;
        for (int e = 0; e < N_EXPERTS; ++e) s += expf(lt[t][e] - m);
        const float rs = 1.f / s;
        smax[t] = m; srs[t] = rs;
        float ex[TOP_K]; float wsum = 0.f;
#pragma unroll
        for (int i = 0; i < TOP_K; ++i) { ex[i] = expf(tv[i] - tv[0]); wsum += ex[i]; }
        const float rw = 1.f / wsum;
        const int tok = m0 + t;
#pragma unroll
        for (int i = 0; i < TOP_K; ++i) {
            out_idx[(size_t)tok * TOP_K + i] = (float)ti[i];
            out_w  [(size_t)tok * TOP_K + i] = ex[i] * rw;
        }
    }
    __syncthreads();
#pragma unroll
    for (int rep = 0; rep < 2; ++rep) {
        const int f = rep * (512 * 4) + tid * 4;
        const int t = f >> 6;
        const int e = f & 63;
        const float l0 = lt[t][e], l1 = lt[t][e+1], l2 = lt[t][e+2], l3 = lt[t][e+3];
        const float mm = smax[t], rr = srs[t];
        float4 pv = make_float4(expf(l0-mm)*rr, expf(l1-mm)*rr, expf(l2-mm)*rr, expf(l3-mm)*rr);
        float4 lv = make_float4(l0, l1, l2, l3);
        const size_t gbase = (size_t)m0 * N_EXPERTS + f;
        *(float4*)(out_p + gbase) = pv;
        *(float4*)(out_l + gbase) = lv;
    }
}

extern "C" void kernel_launch(void* const* d_in, const int* in_sizes, int n_in,
                              void* d_out, int out_size, void* d_ws, size_t ws_size,
                              hipStream_t stream) {
    const float* x  = (const float*)d_in[0];
    const float* gw = (const float*)d_in[1];
    float* out = (float*)d_out;
    if (ws_size >= (size_t)WS_NEED) {
        unsigned* wp = (unsigned*)d_ws;
        pack_w_kernel<<<dim3(WS_NEED / 4 / 256), dim3(256), 0, stream>>>(gw, wp);
        router_mfma<<<dim3(N_TOKENS / 16), dim3(NTHREADS), 0, stream>>>(x, wp, out);
    } else {
        router_fallback<<<dim3(N_TOKENS / 64), dim3(512), 0, stream>>>(x, gw, out);
    }
}